// Round 10
// baseline (604.271 us; speedup 1.0000x reference)
//
#include <hip/hip_runtime.h>
#include <hip/hip_bf16.h>
#include <stdint.h>

// Problem dims
#define Bz 64
#define Tz 512
#define Iz 256
#define Hz 256
#define G4z 1024
#define YSZ (Bz*Tz*Hz)          // 8388608

typedef __bf16 bf16;
typedef float  f32x4  __attribute__((ext_vector_type(4)));
typedef int    i32x4  __attribute__((ext_vector_type(4)));
typedef __bf16 bf16x8 __attribute__((ext_vector_type(8)));
typedef __bf16 bf16x4 __attribute__((ext_vector_type(4)));

// ---------------- workspace layout ----------------
#define XP_OFF  0u                      // bf16 xp [32768][1024] = 67108864 B
#define XB_OFF  67108864u               // bf16 x  [32768][256]  = 16777216 B
#define WI_OFF  83886080u               // bf16 W_ih [1024][256] = 524288 B

// ---------------- fp32 -> bf16 convert ----------------
__global__ __launch_bounds__(256) void cvt_f32_bf16(const float* __restrict__ in,
                                                    bf16* __restrict__ out, int n4) {
  int i = blockIdx.x * blockDim.x + threadIdx.x;
  if (i >= n4) return;
  float4 v = reinterpret_cast<const float4*>(in)[i];
  bf16x4 o = {(__bf16)v.x, (__bf16)v.y, (__bf16)v.z, (__bf16)v.w};
  *reinterpret_cast<bf16x4*>(out + (size_t)i*4) = o;
}

// ---------------- x_proj GEMM: A[m=b*T+t][256] @ W_ih^T + bias -> xp[m][1024] bf16 ----------------
__global__ __launch_bounds__(256) void xproj_gemm(const bf16* __restrict__ A,
                                                  const bf16* __restrict__ Bw,
                                                  const float* __restrict__ b_ih,
                                                  const float* __restrict__ b_hh,
                                                  bf16* __restrict__ xp) {
  constexpr int K = 256;
  __shared__ __align__(16) bf16 As[128*32];
  __shared__ __align__(16) bf16 Bs[128*32];
  __shared__ float bias_s[128];
  const int bm = blockIdx.x >> 3;
  const int bn = blockIdx.x & 7;
  const int m0 = bm * 128, n0 = bn * 128;
  const int tid = threadIdx.x;
  if (tid < 128) bias_s[tid] = b_ih[n0 + tid] + b_hh[n0 + tid];
  const int w = tid >> 6, lane = tid & 63;
  const int wm = w >> 1, wn = w & 1;
  const int lr = lane & 15, lk = lane >> 4;
  f32x4 acc[4][4] = {};
  for (int kt = 0; kt < 8; ++kt) {
#pragma unroll
    for (int p = 0; p < 2; ++p) {
      int elem = p * 256 + tid;
      int row = elem >> 2, c = elem & 3;
      uint4 va = *reinterpret_cast<const uint4*>(A + (size_t)(m0 + row) * K + kt*32 + c*8);
      *reinterpret_cast<uint4*>((char*)As + row*64 + ((c ^ (row & 3)) * 16)) = va;
      uint4 vb = *reinterpret_cast<const uint4*>(Bw + (size_t)(n0 + row) * K + kt*32 + c*8);
      *reinterpret_cast<uint4*>((char*)Bs + row*64 + ((c ^ (row & 3)) * 16)) = vb;
    }
    __syncthreads();
    bf16x8 fa[4], fb[4];
#pragma unroll
    for (int f = 0; f < 4; ++f) {
      int ra = wm*64 + f*16 + lr;
      fa[f] = *reinterpret_cast<const bf16x8*>((char*)As + ra*64 + ((lk ^ (ra & 3)) * 16));
      int rb = wn*64 + f*16 + lr;
      fb[f] = *reinterpret_cast<const bf16x8*>((char*)Bs + rb*64 + ((lk ^ (rb & 3)) * 16));
    }
#pragma unroll
    for (int fi = 0; fi < 4; ++fi)
#pragma unroll
      for (int fj = 0; fj < 4; ++fj)
        acc[fi][fj] = __builtin_amdgcn_mfma_f32_16x16x32_bf16(fa[fi], fb[fj], acc[fi][fj], 0, 0, 0);
    __syncthreads();
  }
#pragma unroll
  for (int fi = 0; fi < 4; ++fi)
#pragma unroll
    for (int fj = 0; fj < 4; ++fj) {
      int col = n0 + wn*64 + fj*16 + lr;
      float bias = bias_s[wn*64 + fj*16 + lr];
#pragma unroll
      for (int v = 0; v < 4; ++v) {
        int row = m0 + wm*64 + fi*16 + lk*4 + v;
        xp[(size_t)row * 1024 + col] = (__bf16)(acc[fi][fj][v] + bias);
      }
    }
}

// ---------------- recurrence: 1 batch/block, pair-local gates, 1 barrier/step ----------------
// Thread pair (2h,2h+1) in the SAME wave owns all 4 gates of h-index h:
// even thread rows {h(i), 512+h(g)}, odd rows {256+h(f), 768+h(o)}.
// Gates exchanged via 2x shfl_xor(1) (no LDS, no barrier); nonlin computed
// redundantly by both lanes; h_s parity double-buffer -> ONE barrier/step.

__device__ __forceinline__ float fast_sigmoid(float x) {
  return __builtin_amdgcn_rcpf(1.f + __expf(-x));
}
__device__ __forceinline__ float fast_tanh(float x) {
  return 1.f - 2.f * __builtin_amdgcn_rcpf(__expf(2.f * x) + 1.f);
}
__device__ __forceinline__ int sdot4f(int a, int b, int c) {
#if __has_builtin(__builtin_amdgcn_sdot4)
  return __builtin_amdgcn_sdot4(a, b, c, false);
#else
  int r = c;
  r += (int)(signed char)(a)        * (int)(signed char)(b);
  r += (int)(signed char)(a >> 8)   * (int)(signed char)(b >> 8);
  r += (int)(signed char)(a >> 16)  * (int)(signed char)(b >> 16);
  r += (int)(signed char)(a >> 24)  * (int)(signed char)(b >> 24);
  return r;
#endif
}
#define SCL (1.0f / (2032.0f * 127.0f))

__global__ __launch_bounds__(512, 2) void lstm_rec(const bf16* __restrict__ xp,
                                                   const float* __restrict__ Whh,
                                                   float* __restrict__ out) {
  __shared__ __align__(16) char h_s[2][256];   // i8 h, parity double-buffered
  const int tid = threadIdx.x;
  const int b = blockIdx.x;
  const int h = tid >> 1;                      // this pair's h index
  const int sel = tid & 1;                     // 0: rows {i,g}, 1: rows {f,o}
  const int r0 = sel * 256 + h;                // i- or f-gate row
  const int r1 = r0 + 512;                     // g- or o-gate row

  // ---- quantize W rows {r0, r1} into registers (64+64 dwords)
  int w0[64], w1[64];
  {
    const float* wp0 = Whh + (size_t)r0 * 256;
    const float* wp1 = Whh + (size_t)r1 * 256;
#pragma unroll
    for (int d = 0; d < 64; ++d) {
      float4 f = *reinterpret_cast<const float4*>(wp0 + d*4);
      int q0 = (int)rintf(f.x * 2032.f), q1 = (int)rintf(f.y * 2032.f);
      int q2 = (int)rintf(f.z * 2032.f), q3 = (int)rintf(f.w * 2032.f);
      w0[d] = (q0 & 255) | ((q1 & 255) << 8) | ((q2 & 255) << 16) | ((q3 & 255) << 24);
      float4 g = *reinterpret_cast<const float4*>(wp1 + d*4);
      int p0 = (int)rintf(g.x * 2032.f), p1 = (int)rintf(g.y * 2032.f);
      int p2 = (int)rintf(g.z * 2032.f), p3 = (int)rintf(g.w * 2032.f);
      w1[d] = (p0 & 255) | ((p1 & 255) << 8) | ((p2 & 255) << 16) | ((p3 & 255) << 24);
    }
  }
  if (tid < 64) reinterpret_cast<int*>(h_s[0])[tid] = 0;    // h0 = 0

  const bf16* xprow = xp + (size_t)b * Tz * 1024;
  unsigned short xv0 = *(const unsigned short*)(xprow + r0);
  unsigned short xv1 = *(const unsigned short*)(xprow + r1);

  float cc = 0.f;
  __syncthreads();

  for (int t = 0; t < Tz; ++t) {
    const char* hb = h_s[t & 1];
    // ---- GEMV: 2 rows x 256 k, h broadcast from LDS (4 indep chains per row)
    int a0=0,a1=0,a2=0,a3=0, d0=0,d1=0,d2=0,d3=0;
#pragma unroll
    for (int d = 0; d < 16; ++d) {
      i32x4 hv = *reinterpret_cast<const i32x4*>(hb + d*16);
      a0 = sdot4f(hv[0], w0[4*d+0], a0);
      a1 = sdot4f(hv[1], w0[4*d+1], a1);
      a2 = sdot4f(hv[2], w0[4*d+2], a2);
      a3 = sdot4f(hv[3], w0[4*d+3], a3);
      d0 = sdot4f(hv[0], w1[4*d+0], d0);
      d1 = sdot4f(hv[1], w1[4*d+1], d1);
      d2 = sdot4f(hv[2], w1[4*d+2], d2);
      d3 = sdot4f(hv[3], w1[4*d+3], d3);
    }
    float g0 = (float)((a0 + a1) + (a2 + a3)) * SCL + __uint_as_float((unsigned)xv0 << 16);
    float g1 = (float)((d0 + d1) + (d2 + d3)) * SCL + __uint_as_float((unsigned)xv1 << 16);
    // ---- prefetch next xp (latency hides under shfl+nonlin+barrier)
    if (t < Tz - 1) {
      xv0 = *(const unsigned short*)(xprow + (size_t)(t+1)*1024 + r0);
      xv1 = *(const unsigned short*)(xprow + (size_t)(t+1)*1024 + r1);
    }
    // ---- pair exchange: even has {i,g}, odd has {f,o}
    float p0 = __shfl_xor(g0, 1);
    float p1 = __shfl_xor(g1, 1);
    float vi = sel ? p0 : g0;
    float vf = sel ? g0 : p0;
    float vg = sel ? p1 : g1;
    float vo = sel ? g1 : p1;
    // ---- nonlin (redundant on both lanes; bit-identical)
    float gi = fast_sigmoid(vi);
    float gf = fast_sigmoid(vf);
    float gg = fast_tanh(vg);
    float go = fast_sigmoid(vo);
    cc = gf * cc + gi * gg;
    float hv = go * fast_tanh(cc);
    if (!sel) {
      out[((size_t)b * Tz + t) * 256 + h] = hv;
      if (t < Tz - 1) {
        h_s[(t & 1) ^ 1][h] = (char)(int)rintf(hv * 127.f);
      } else {
        out[(size_t)YSZ + (size_t)b * 256 + h] = hv;
        out[(size_t)YSZ + 16384 + (size_t)b * 256 + h] = cc;
      }
    }
    __syncthreads();
  }
}

extern "C" void kernel_launch(void* const* d_in, const int* in_sizes, int n_in,
                              void* d_out, int out_size, void* d_ws, size_t ws_size,
                              hipStream_t stream) {
  const float* x    = (const float*)d_in[0];
  const float* W_ih = (const float*)d_in[1];
  const float* W_hh = (const float*)d_in[2];
  const float* b_ih = (const float*)d_in[3];
  const float* b_hh = (const float*)d_in[4];
  float* out = (float*)d_out;
  char* ws = (char*)d_ws;

  bf16* xp  = (bf16*)(ws + XP_OFF);
  bf16* xb  = (bf16*)(ws + XB_OFF);
  bf16* wib = (bf16*)(ws + WI_OFF);

  cvt_f32_bf16<<<8192, 256, 0, stream>>>(x, xb, (Bz*Tz*Iz) / 4);
  cvt_f32_bf16<<<256, 256, 0, stream>>>(W_ih, wib, (G4z*Iz) / 4);
  xproj_gemm<<<2048, 256, 0, stream>>>(xb, wib, b_ih, b_hh, xp);
  lstm_rec<<<64, 512, 0, stream>>>(xp, W_hh, out);
}

// Round 11
// 580.813 us; speedup vs baseline: 1.0404x; 1.0404x over previous
//
#include <hip/hip_runtime.h>
#include <hip/hip_bf16.h>
#include <stdint.h>

// Problem dims
#define Bz 64
#define Tz 512
#define Iz 256
#define Hz 256
#define G4z 1024
#define YSZ (Bz*Tz*Hz)          // 8388608

typedef __bf16 bf16;
typedef float  f32x4  __attribute__((ext_vector_type(4)));
typedef int    i32x4  __attribute__((ext_vector_type(4)));
typedef __bf16 bf16x8 __attribute__((ext_vector_type(8)));
typedef __bf16 bf16x4 __attribute__((ext_vector_type(4)));

// ---------------- workspace layout ----------------
#define XP_OFF  0u                      // bf16 xp [32768][1024] = 67108864 B
#define XB_OFF  67108864u               // bf16 x  [32768][256]  = 16777216 B
#define WI_OFF  83886080u               // bf16 W_ih [1024][256] = 524288 B

// ---------------- fp32 -> bf16 convert ----------------
__global__ __launch_bounds__(256) void cvt_f32_bf16(const float* __restrict__ in,
                                                    bf16* __restrict__ out, int n4) {
  int i = blockIdx.x * blockDim.x + threadIdx.x;
  if (i >= n4) return;
  float4 v = reinterpret_cast<const float4*>(in)[i];
  bf16x4 o = {(__bf16)v.x, (__bf16)v.y, (__bf16)v.z, (__bf16)v.w};
  *reinterpret_cast<bf16x4*>(out + (size_t)i*4) = o;
}

// ---------------- x_proj GEMM: A[m=b*T+t][256] @ W_ih^T + bias -> xp[m][1024] bf16 ----------------
__global__ __launch_bounds__(256) void xproj_gemm(const bf16* __restrict__ A,
                                                  const bf16* __restrict__ Bw,
                                                  const float* __restrict__ b_ih,
                                                  const float* __restrict__ b_hh,
                                                  bf16* __restrict__ xp) {
  constexpr int K = 256;
  __shared__ __align__(16) bf16 As[128*32];
  __shared__ __align__(16) bf16 Bs[128*32];
  __shared__ float bias_s[128];
  const int bm = blockIdx.x >> 3;
  const int bn = blockIdx.x & 7;
  const int m0 = bm * 128, n0 = bn * 128;
  const int tid = threadIdx.x;
  if (tid < 128) bias_s[tid] = b_ih[n0 + tid] + b_hh[n0 + tid];
  const int w = tid >> 6, lane = tid & 63;
  const int wm = w >> 1, wn = w & 1;
  const int lr = lane & 15, lk = lane >> 4;
  f32x4 acc[4][4] = {};
  for (int kt = 0; kt < 8; ++kt) {
#pragma unroll
    for (int p = 0; p < 2; ++p) {
      int elem = p * 256 + tid;
      int row = elem >> 2, c = elem & 3;
      uint4 va = *reinterpret_cast<const uint4*>(A + (size_t)(m0 + row) * K + kt*32 + c*8);
      *reinterpret_cast<uint4*>((char*)As + row*64 + ((c ^ (row & 3)) * 16)) = va;
      uint4 vb = *reinterpret_cast<const uint4*>(Bw + (size_t)(n0 + row) * K + kt*32 + c*8);
      *reinterpret_cast<uint4*>((char*)Bs + row*64 + ((c ^ (row & 3)) * 16)) = vb;
    }
    __syncthreads();
    bf16x8 fa[4], fb[4];
#pragma unroll
    for (int f = 0; f < 4; ++f) {
      int ra = wm*64 + f*16 + lr;
      fa[f] = *reinterpret_cast<const bf16x8*>((char*)As + ra*64 + ((lk ^ (ra & 3)) * 16));
      int rb = wn*64 + f*16 + lr;
      fb[f] = *reinterpret_cast<const bf16x8*>((char*)Bs + rb*64 + ((lk ^ (rb & 3)) * 16));
    }
#pragma unroll
    for (int fi = 0; fi < 4; ++fi)
#pragma unroll
      for (int fj = 0; fj < 4; ++fj)
        acc[fi][fj] = __builtin_amdgcn_mfma_f32_16x16x32_bf16(fa[fi], fb[fj], acc[fi][fj], 0, 0, 0);
    __syncthreads();
  }
#pragma unroll
  for (int fi = 0; fi < 4; ++fi)
#pragma unroll
    for (int fj = 0; fj < 4; ++fj) {
      int col = n0 + wn*64 + fj*16 + lr;
      float bias = bias_s[wn*64 + fj*16 + lr];
#pragma unroll
      for (int v = 0; v < 4; ++v) {
        int row = m0 + wm*64 + fi*16 + lk*4 + v;
        xp[(size_t)row * 1024 + col] = (__bf16)(acc[fi][fj][v] + bias);
      }
    }
}

// ---------------- recurrence: 1 batch/block, 1024 thr (4 waves/SIMD), 1 row/thread ----------------
// Thread tid = 4h+q owns gate row r = q*256+h (q in {i,f,g,o}): 64 W regs.
// Per step: 64 sdot4 (4 indep chains) -> gates[tid] in LDS (conflict-free),
// barrier, nonlin on tid<256 (one float4 read = i,f,g,o), h_s i8 republish,
// barrier. 4 waves/SIMD hide LDS/dep/barrier latency (r10 had only 2).

__device__ __forceinline__ float fast_sigmoid(float x) {
  return __builtin_amdgcn_rcpf(1.f + __expf(-x));
}
__device__ __forceinline__ float fast_tanh(float x) {
  return 1.f - 2.f * __builtin_amdgcn_rcpf(__expf(2.f * x) + 1.f);
}
__device__ __forceinline__ int sdot4f(int a, int b, int c) {
#if __has_builtin(__builtin_amdgcn_sdot4)
  return __builtin_amdgcn_sdot4(a, b, c, false);
#else
  int r = c;
  r += (int)(signed char)(a)        * (int)(signed char)(b);
  r += (int)(signed char)(a >> 8)   * (int)(signed char)(b >> 8);
  r += (int)(signed char)(a >> 16)  * (int)(signed char)(b >> 16);
  r += (int)(signed char)(a >> 24)  * (int)(signed char)(b >> 24);
  return r;
#endif
}
#define SCL (1.0f / (2032.0f * 127.0f))

__global__ __launch_bounds__(1024, 1) void lstm_rec(const bf16* __restrict__ xp,
                                                    const float* __restrict__ Whh,
                                                    float* __restrict__ out) {
  __shared__ __align__(16) char  h_s[256];     // i8 h (single buffer; bar1/bar2 fence WAR)
  __shared__ __align__(16) float gates[1024];
  const int tid = threadIdx.x;
  const int b = blockIdx.x;
  const int h = tid >> 2;                      // h index (0..255)
  const int q = tid & 3;                       // gate: 0=i,1=f,2=g,3=o
  const int r = q * 256 + h;                   // gate row

  // ---- quantize W row r into 64 registers
  int w[64];
  {
    const float* wp = Whh + (size_t)r * 256;
#pragma unroll
    for (int d = 0; d < 64; ++d) {
      float4 f = *reinterpret_cast<const float4*>(wp + d*4);
      int q0 = (int)rintf(f.x * 2032.f), q1 = (int)rintf(f.y * 2032.f);
      int q2 = (int)rintf(f.z * 2032.f), q3 = (int)rintf(f.w * 2032.f);
      w[d] = (q0 & 255) | ((q1 & 255) << 8) | ((q2 & 255) << 16) | ((q3 & 255) << 24);
    }
  }
  if (tid < 64) reinterpret_cast<int*>(h_s)[tid] = 0;    // h0 = 0

  const bf16* xprow = xp + (size_t)b * Tz * 1024;
  unsigned short xv = *(const unsigned short*)(xprow + r);

  float cc = 0.f;                              // c for h-idx tid (tid<256 only)
  __syncthreads();

  for (int t = 0; t < Tz; ++t) {
    // ---- GEMV row r over k=256: h broadcast from LDS, 4 indep chains
    int a0 = 0, a1 = 0, a2 = 0, a3 = 0;
#pragma unroll
    for (int d = 0; d < 16; ++d) {
      i32x4 hv = *reinterpret_cast<const i32x4*>(h_s + d*16);
      a0 = sdot4f(hv[0], w[4*d+0], a0);
      a1 = sdot4f(hv[1], w[4*d+1], a1);
      a2 = sdot4f(hv[2], w[4*d+2], a2);
      a3 = sdot4f(hv[3], w[4*d+3], a3);
    }
    float xcur = __uint_as_float((unsigned)xv << 16);
    if (t < Tz - 1)
      xv = *(const unsigned short*)(xprow + (size_t)(t+1)*1024 + r);   // prefetch
    gates[tid] = (float)((a0 + a1) + (a2 + a3)) * SCL + xcur;
    __syncthreads();                            // gates ready; h_s reads done

    if (tid < 256) {
      float4 g4 = *reinterpret_cast<const float4*>(gates + tid*4);   // (i,f,g,o)
      float gi = fast_sigmoid(g4.x);
      float gf = fast_sigmoid(g4.y);
      float gg = fast_tanh(g4.z);
      float go = fast_sigmoid(g4.w);
      cc = gf * cc + gi * gg;
      float hv = go * fast_tanh(cc);
      out[((size_t)b * Tz + t) * 256 + tid] = hv;
      if (t < Tz - 1) {
        h_s[tid] = (char)(int)rintf(hv * 127.f);
      } else {
        out[(size_t)YSZ + (size_t)b * 256 + tid] = hv;
        out[(size_t)YSZ + 16384 + (size_t)b * 256 + tid] = cc;
      }
    }
    __syncthreads();                            // h(t) staged for next step
  }
}

extern "C" void kernel_launch(void* const* d_in, const int* in_sizes, int n_in,
                              void* d_out, int out_size, void* d_ws, size_t ws_size,
                              hipStream_t stream) {
  const float* x    = (const float*)d_in[0];
  const float* W_ih = (const float*)d_in[1];
  const float* W_hh = (const float*)d_in[2];
  const float* b_ih = (const float*)d_in[3];
  const float* b_hh = (const float*)d_in[4];
  float* out = (float*)d_out;
  char* ws = (char*)d_ws;

  bf16* xp  = (bf16*)(ws + XP_OFF);
  bf16* xb  = (bf16*)(ws + XB_OFF);
  bf16* wib = (bf16*)(ws + WI_OFF);

  cvt_f32_bf16<<<8192, 256, 0, stream>>>(x, xb, (Bz*Tz*Iz) / 4);
  cvt_f32_bf16<<<256, 256, 0, stream>>>(W_ih, wib, (G4z*Iz) / 4);
  xproj_gemm<<<2048, 256, 0, stream>>>(xb, wib, b_ih, b_hh, xp);
  lstm_rec<<<64, 1024, 0, stream>>>(xp, W_hh, out);
}